// Round 1
// baseline (502.333 us; speedup 1.0000x reference)
//
#include <hip/hip_runtime.h>
#include <hip/hip_bf16.h>
#include <cstdint>

typedef unsigned short U16;
typedef float f32x4 __attribute__((ext_vector_type(4)));
typedef __bf16 bf16x8 __attribute__((ext_vector_type(8)));

#define DEVINL __device__ __forceinline__

DEVINL U16 f2bf(float f) {
    unsigned u = __float_as_uint(f);
    return (U16)((u + 0x7FFFu + ((u >> 16) & 1u)) >> 16);  // RN-even
}
DEVINL float bf2f(U16 s) { return __uint_as_float(((unsigned)s) << 16); }

DEVINL void gld16(const void* g, void* l) {
    __builtin_amdgcn_global_load_lds(
        (const __attribute__((address_space(1))) void*)g,
        (__attribute__((address_space(3))) void*)l, 16, 0, 0);
}

// ---------------- weight transpose + cast: wt[n][k] = (bf16) w[k][n] ----------------
__global__ __launch_bounds__(256) void tcast_kernel(const float* __restrict__ w,
                                                    U16* __restrict__ wt, int K, int N) {
    __shared__ float tile[32][33];
    int n0 = blockIdx.x * 32, k0 = blockIdx.y * 32;
    int tx = threadIdx.x, ty = threadIdx.y;  // 32 x 8
#pragma unroll
    for (int i = 0; i < 32; i += 8) tile[ty + i][tx] = w[(size_t)(k0 + ty + i) * N + (n0 + tx)];
    __syncthreads();
#pragma unroll
    for (int i = 0; i < 32; i += 8) wt[(size_t)(n0 + ty + i) * K + (k0 + tx)] = f2bf(tile[tx][ty + i]);
}

// ---------------- LayerNorm over 512, one wave per row, bf16 out ----------------
__global__ __launch_bounds__(256) void ln_kernel(const float* __restrict__ x,
                                                 const float* __restrict__ g,
                                                 const float* __restrict__ b,
                                                 U16* __restrict__ out) {
    int lane = threadIdx.x & 63;
    size_t row = (size_t)blockIdx.x * 4 + (threadIdx.x >> 6);
    const float4* xr = (const float4*)(x + row * 512);
    float4 v0 = xr[lane], v1 = xr[lane + 64];
    float s = (v0.x + v0.y) + (v0.z + v0.w) + (v1.x + v1.y) + (v1.z + v1.w);
    float sq = (v0.x * v0.x + v0.y * v0.y + v0.z * v0.z + v0.w * v0.w) +
               (v1.x * v1.x + v1.y * v1.y + v1.z * v1.z + v1.w * v1.w);
#pragma unroll
    for (int m = 1; m < 64; m <<= 1) { s += __shfl_xor(s, m); sq += __shfl_xor(sq, m); }
    float mu = s * (1.f / 512.f);
    float var = sq * (1.f / 512.f) - mu * mu;
    float rs = rsqrtf(var + 1e-5f);
    const float4* g4 = (const float4*)g;
    const float4* b4 = (const float4*)b;
    float4 gv = g4[lane], bv = b4[lane];
    ushort4 o;
    o.x = f2bf((v0.x - mu) * rs * gv.x + bv.x);
    o.y = f2bf((v0.y - mu) * rs * gv.y + bv.y);
    o.z = f2bf((v0.z - mu) * rs * gv.z + bv.z);
    o.w = f2bf((v0.w - mu) * rs * gv.w + bv.w);
    ((ushort4*)(out + row * 512))[lane] = o;
    gv = g4[lane + 64]; bv = b4[lane + 64];
    o.x = f2bf((v1.x - mu) * rs * gv.x + bv.x);
    o.y = f2bf((v1.y - mu) * rs * gv.y + bv.y);
    o.z = f2bf((v1.z - mu) * rs * gv.z + bv.z);
    o.w = f2bf((v1.w - mu) * rs * gv.w + bv.w);
    ((ushort4*)(out + row * 512))[lane + 64] = o;
}

// ---------------- GEMM: C[M,N] = A[M,K](bf16) * Bt[N,K](bf16)^T + bias, epilogues ----------------
// EPI 0: bf16 out (bias)         -> outb
// EPI 1: fp32 out (bias + resid) -> outf
// EPI 2: bf16 out (bias + gelu)  -> outb
template <int EPI>
__global__ __launch_bounds__(256) void gemm_bt(const U16* __restrict__ A,
                                               const U16* __restrict__ Bt,
                                               const float* __restrict__ bias,
                                               const float* __restrict__ resid,
                                               U16* __restrict__ outb,
                                               float* __restrict__ outf,
                                               int M, int N, int K) {
    __shared__ __align__(16) U16 As[128 * 32];
    __shared__ __align__(16) U16 Bs[128 * 32];
    const int tid = threadIdx.x;
    const int lane = tid & 63, wv = tid >> 6;
    const int lo = lane & 15, hi = lane >> 4;
    const int bn = blockIdx.x, bm = blockIdx.y;
    const int wm = wv >> 1, wn = wv & 1;  // 2x2 wave grid, 64x64 per wave

    // staging: per wave, rows [wv*32, wv*32+32); LDS dst = wave-uniform base + lane*16B
    const int srow = wv * 32 + (lane >> 2);
    const int sk = (lane & 3) * 8;

    const U16* ga = A + (size_t)(bm * 128 + srow) * K + sk;
    const U16* gb = Bt + (size_t)(bn * 128 + srow) * K + sk;
    U16* la = &As[srow * 32 + sk];
    U16* lb = &Bs[srow * 32 + sk];

    f32x4 acc[4][4] = {};

    for (int k0 = 0; k0 < K; k0 += 32) {
        gld16(ga, la);
        gld16(ga + (size_t)16 * K, la + 16 * 32);
        gld16(gb, lb);
        gld16(gb + (size_t)16 * K, lb + 16 * 32);
        ga += 32; gb += 32;
        __syncthreads();
        bf16x8 af[4], bfr[4];
#pragma unroll
        for (int i = 0; i < 4; i++) af[i] = *(const bf16x8*)&As[(wm * 64 + i * 16 + lo) * 32 + hi * 8];
#pragma unroll
        for (int j = 0; j < 4; j++) bfr[j] = *(const bf16x8*)&Bs[(wn * 64 + j * 16 + lo) * 32 + hi * 8];
#pragma unroll
        for (int i = 0; i < 4; i++)
#pragma unroll
            for (int j = 0; j < 4; j++)
                acc[i][j] = __builtin_amdgcn_mfma_f32_16x16x32_bf16(af[i], bfr[j], acc[i][j], 0, 0, 0);
        __syncthreads();
    }

    const int row0 = bm * 128 + wm * 64 + hi * 4;
    const int col0 = bn * 128 + wn * 64 + lo;
#pragma unroll
    for (int j = 0; j < 4; j++) {
        const int col = col0 + j * 16;
        const float bc = bias[col];
#pragma unroll
        for (int i = 0; i < 4; i++) {
#pragma unroll
            for (int r = 0; r < 4; r++) {
                const size_t idx = (size_t)(row0 + i * 16 + r) * N + col;
                float v = acc[i][j][r] + bc;
                if (EPI == 0) {
                    outb[idx] = f2bf(v);
                } else if (EPI == 1) {
                    outf[idx] = v + resid[idx];
                } else {
                    v = 0.5f * v * (1.f + erff(v * 0.70710678118654752f));
                    outb[idx] = f2bf(v);
                }
            }
        }
    }
}

// ---------------- windowed attention: one block per (window, head) ----------------
// qkv: [32768][1536] bf16, layout [3][8][64] in last dim. o: [32768][512] bf16.
__global__ __launch_bounds__(256) void attn_kernel(const U16* __restrict__ qkv,
                                                   U16* __restrict__ o) {
    const int blk = blockIdx.x;
    const int w = blk >> 3, h = blk & 7;
    const int tid = threadIdx.x;
    const int lane = tid & 63, wv = tid >> 6;
    const int lo = lane & 15, hi = lane >> 4;

    __shared__ __align__(16) U16 Qs[64][72];
    __shared__ __align__(16) U16 Ks[64][72];
    __shared__ __align__(16) U16 Vt[64][72];  // V transposed: Vt[d][j]
    __shared__ __align__(16) U16 Ps[4][16][72];

    {
        const int r = tid >> 2;
        const int c0 = (tid & 3) << 4;
        const U16* p = qkv + (size_t)(w * 64 + r) * 1536 + h * 64 + c0;
        // K: direct vector copy
        *(bf16x8*)&Ks[r][c0] = *(const bf16x8*)(p + 512);
        *(bf16x8*)&Ks[r][c0 + 8] = *(const bf16x8*)(p + 520);
        // V: transpose (scalar)
        const U16* pv = p + 1024;
#pragma unroll
        for (int i = 0; i < 16; i++) Vt[c0 + i][r] = pv[i];
        // Q: scale by 1/8 (exact in bf16)
#pragma unroll
        for (int i = 0; i < 16; i++) Qs[r][c0 + i] = f2bf(bf2f(p[i]) * 0.125f);
    }
    __syncthreads();

    const int rb = wv * 16;  // this wave's 16 score rows
    f32x4 s[4] = {};
#pragma unroll
    for (int dc = 0; dc < 64; dc += 32) {
        bf16x8 a = *(const bf16x8*)&Qs[rb + lo][dc + hi * 8];
#pragma unroll
        for (int jb = 0; jb < 4; jb++) {
            bf16x8 bfr = *(const bf16x8*)&Ks[jb * 16 + lo][dc + hi * 8];
            s[jb] = __builtin_amdgcn_mfma_f32_16x16x32_bf16(a, bfr, s[jb], 0, 0, 0);
        }
    }
    // softmax: row = rb + hi*4 + r, data spread over 16 lanes (lo) x 4 col-blocks
#pragma unroll
    for (int r = 0; r < 4; r++) {
        float m = fmaxf(fmaxf(s[0][r], s[1][r]), fmaxf(s[2][r], s[3][r]));
#pragma unroll
        for (int msk = 1; msk < 16; msk <<= 1) m = fmaxf(m, __shfl_xor(m, msk));
        float e[4], sum = 0.f;
#pragma unroll
        for (int jb = 0; jb < 4; jb++) { e[jb] = expf(s[jb][r] - m); sum += e[jb]; }
#pragma unroll
        for (int msk = 1; msk < 16; msk <<= 1) sum += __shfl_xor(sum, msk);
        float inv = 1.f / sum;
#pragma unroll
        for (int jb = 0; jb < 4; jb++) Ps[wv][hi * 4 + r][jb * 16 + lo] = f2bf(e[jb] * inv);
    }
    __syncthreads();

    // O = P @ V  (A from Ps, B from Vt)
    f32x4 oa[4] = {};
#pragma unroll
    for (int jc = 0; jc < 64; jc += 32) {
        bf16x8 a = *(const bf16x8*)&Ps[wv][lo][jc + hi * 8];
#pragma unroll
        for (int db = 0; db < 4; db++) {
            bf16x8 bfr = *(const bf16x8*)&Vt[db * 16 + lo][jc + hi * 8];
            oa[db] = __builtin_amdgcn_mfma_f32_16x16x32_bf16(a, bfr, oa[db], 0, 0, 0);
        }
    }
#pragma unroll
    for (int db = 0; db < 4; db++)
#pragma unroll
        for (int r = 0; r < 4; r++)
            o[(size_t)(w * 64 + rb + hi * 4 + r) * 512 + h * 64 + db * 16 + lo] = f2bf(oa[db][r]);
}

// ---------------- launch ----------------
extern "C" void kernel_launch(void* const* d_in, const int* in_sizes, int n_in,
                              void* d_out, int out_size, void* d_ws, size_t ws_size,
                              hipStream_t stream) {
    const float* x = (const float*)d_in[0];
    const float* ln1_g = (const float*)d_in[1];
    const float* ln1_b = (const float*)d_in[2];
    const float* qkv_w = (const float*)d_in[3];
    const float* qkv_b = (const float*)d_in[4];
    const float* proj_w = (const float*)d_in[5];
    const float* proj_b = (const float*)d_in[6];
    const float* ln2_g = (const float*)d_in[7];
    const float* ln2_b = (const float*)d_in[8];
    const float* fc1_w = (const float*)d_in[9];
    const float* fc1_b = (const float*)d_in[10];
    const float* fc2_w = (const float*)d_in[11];
    const float* fc2_b = (const float*)d_in[12];
    float* out = (float*)d_out;

    // ws layout (bytes): [0,32MiB): h -> attn_o -> h2 ; [32MiB,160MiB): qkv -> fc1_act ;
    // [160MiB, +6MiB): bf16 transposed weights. x2 residual lives in d_out (fp32).
    char* ws = (char*)d_ws;
    U16* hbuf = (U16*)ws;                               // 32768*512 bf16
    U16* big = (U16*)(ws + 33554432);                   // 32768*2048 bf16 max
    U16* wt_qkv = (U16*)(ws + 33554432 + 134217728);    // 1536*512
    U16* wt_proj = wt_qkv + 1536 * 512;                 // 512*512
    U16* wt_fc1 = wt_proj + 512 * 512;                  // 2048*512
    U16* wt_fc2 = wt_fc1 + 2048 * 512;                  // 512*2048

    dim3 tb(32, 8);
    tcast_kernel<<<dim3(1536 / 32, 512 / 32), tb, 0, stream>>>(qkv_w, wt_qkv, 512, 1536);
    tcast_kernel<<<dim3(512 / 32, 512 / 32), tb, 0, stream>>>(proj_w, wt_proj, 512, 512);
    tcast_kernel<<<dim3(2048 / 32, 512 / 32), tb, 0, stream>>>(fc1_w, wt_fc1, 512, 2048);
    tcast_kernel<<<dim3(512 / 32, 2048 / 32), tb, 0, stream>>>(fc2_w, wt_fc2, 2048, 512);

    ln_kernel<<<8192, 256, 0, stream>>>(x, ln1_g, ln1_b, hbuf);
    gemm_bt<0><<<dim3(12, 256), 256, 0, stream>>>(hbuf, wt_qkv, qkv_b, nullptr, big, nullptr, 32768, 1536, 512);
    attn_kernel<<<4096, 256, 0, stream>>>(big, hbuf);
    gemm_bt<1><<<dim3(4, 256), 256, 0, stream>>>(hbuf, wt_proj, proj_b, x, nullptr, out, 32768, 512, 512);
    ln_kernel<<<8192, 256, 0, stream>>>(out, ln2_g, ln2_b, hbuf);
    gemm_bt<2><<<dim3(16, 256), 256, 0, stream>>>(hbuf, wt_fc1, fc1_b, nullptr, big, nullptr, 32768, 2048, 512);
    gemm_bt<1><<<dim3(4, 256), 256, 0, stream>>>(big, wt_fc2, fc2_b, out, nullptr, out, 32768, 512, 2048);
}